// Round 10
// baseline (1759.969 us; speedup 1.0000x reference)
//
#include <hip/hip_runtime.h>
#include <math.h>

#define N_NODES  100000
#define N_HEDGES 100000
#define N_INC    3200000
#define N_LINKS  262144

constexpr int C1 = 128;   // smooth channel width (both smooths run at 128)
constexpr int SCAN_B = 256;
constexpr int SCAN_NB = (N_NODES + SCAN_B - 1) / SCAN_B;   // 391

// ---------------- structure kernels ----------------

__global__ void k_init(int* dv_cnt, int* de_cnt, int* hoff) {
    int i = blockIdx.x * blockDim.x + threadIdx.x;
    if (i < N_NODES)  dv_cnt[i] = 0;
    if (i < N_HEDGES) { de_cnt[i] = 0; hoff[i] = N_INC; }
}

__global__ void k_count(const int* __restrict__ inc_v, const int* __restrict__ inc_e,
                        int* __restrict__ dv_cnt, int* __restrict__ de_cnt,
                        int* __restrict__ hoff) {
    int i = blockIdx.x * blockDim.x + threadIdx.x;
    if (i >= N_INC) return;
    atomicAdd(&dv_cnt[inc_v[i]], 1);
    int e = inc_e[i];
    atomicAdd(&de_cnt[e], 1);
    if (i == 0 || inc_e[i - 1] != e) hoff[e] = i;   // inc_e is sorted
}

__global__ void k_transform(const int* __restrict__ dv_cnt, const int* __restrict__ de_cnt,
                            float* __restrict__ dv_isqrt, float* __restrict__ de_inv) {
    int i = blockIdx.x * blockDim.x + threadIdx.x;
    if (i < N_NODES) {
        int d = dv_cnt[i];
        dv_isqrt[i] = (d > 0) ? 1.0f / sqrtf((float)d) : 0.0f;
    }
    if (i < N_HEDGES) {
        int d = de_cnt[i];
        de_inv[i] = (d > 0) ? 1.0f / (float)d : 0.0f;
    }
}

__global__ void k_scan_blocksum(const int* __restrict__ cnt, int* __restrict__ bsum) {
    __shared__ int s[SCAN_B];
    int i = blockIdx.x * SCAN_B + threadIdx.x;
    s[threadIdx.x] = (i < N_NODES) ? cnt[i] : 0;
    __syncthreads();
    for (int off = SCAN_B / 2; off > 0; off >>= 1) {
        if (threadIdx.x < off) s[threadIdx.x] += s[threadIdx.x + off];
        __syncthreads();
    }
    if (threadIdx.x == 0) bsum[blockIdx.x] = s[0];
}

__global__ void k_scan_bsum(int* __restrict__ bsum) {
    __shared__ int s[512];
    int t = threadIdx.x;
    int own = (t < SCAN_NB) ? bsum[t] : 0;
    s[t] = own;
    __syncthreads();
    for (int off = 1; off < 512; off <<= 1) {
        int v = (t >= off) ? s[t - off] : 0;
        __syncthreads();
        s[t] += v;
        __syncthreads();
    }
    if (t < SCAN_NB) bsum[t] = s[t] - own;   // exclusive prefix of block sums
}

__global__ void k_scan_write(const int* __restrict__ cnt, const int* __restrict__ bpre,
                             int* __restrict__ noff, int* __restrict__ cursor) {
    __shared__ int s[SCAN_B];
    int t = threadIdx.x;
    int i = blockIdx.x * SCAN_B + t;
    int own = (i < N_NODES) ? cnt[i] : 0;
    s[t] = own;
    __syncthreads();
    for (int off = 1; off < SCAN_B; off <<= 1) {
        int v = (t >= off) ? s[t - off] : 0;
        __syncthreads();
        s[t] += v;
        __syncthreads();
    }
    if (i < N_NODES) {
        int excl = s[t] - own + bpre[blockIdx.x];
        noff[i] = excl;
        cursor[i] = excl;
    }
}

__global__ void k_fill_csr(const int* __restrict__ inc_v, const int* __restrict__ inc_e,
                           int* __restrict__ cursor, int* __restrict__ csr_e) {
    int i = blockIdx.x * blockDim.x + threadIdx.x;
    if (i >= N_INC) return;
    int p = atomicAdd(&cursor[inc_v[i]], 1);
    csr_e[p] = inc_e[i];
}

// ---------------- feature segment sums ----------------
// Wave-per-segment; wave split in two 32-lane halves (even/odd incidences),
// float4 per lane (32 lanes x 16B = one full 512B feature row per load).
// 4x unrolled per half -> 8 incidences (4KB) in flight per wave iteration.
// Final cross-half combine: 4x __shfl_xor(...,32).
// Layer-1 instantiations (WS/SV=true) additionally fuse the s = smooth(ones)
// side computation (se/svec) -- edge side pure-VALU on already-loaded
// weights; node side one broadcast 4B load per incidence.

// Out[e][c] = de_inv[e] * sum_j In[inc_v[j]][c] * dv_isqrt[inc_v[j]]
// WS: se[e] = de_inv[e] * sum_j dv_isqrt[inc_v[j]]
template <bool WS>
__global__ void k_gather_edges(const int* __restrict__ hoff, const int* __restrict__ de_cnt,
                               const int* __restrict__ inc_v, const float* __restrict__ in,
                               const float* __restrict__ dv_isqrt, const float* __restrict__ de_inv,
                               float* __restrict__ out, float* __restrict__ se) {
    int gw = (blockIdx.x * blockDim.x + threadIdx.x) >> 6;
    int lane = threadIdx.x & 63;
    if (gw >= N_HEDGES) return;
    int half = lane >> 5;          // 0: even j, 1: odd j
    int l = lane & 31;             // floats 4l..4l+3
    int st = hoff[gw], n = de_cnt[gw];
    float4 acc = {0.f, 0.f, 0.f, 0.f};
    float ws = 0.f;
    int j = half;
    for (; j + 6 < n; j += 8) {
        int v0 = inc_v[st + j],     v1 = inc_v[st + j + 2];
        int v2 = inc_v[st + j + 4], v3 = inc_v[st + j + 6];
        float w0 = dv_isqrt[v0], w1 = dv_isqrt[v1];
        float w2 = dv_isqrt[v2], w3 = dv_isqrt[v3];
        float4 x0 = *reinterpret_cast<const float4*>(in + (size_t)v0 * C1 + l * 4);
        float4 x1 = *reinterpret_cast<const float4*>(in + (size_t)v1 * C1 + l * 4);
        float4 x2 = *reinterpret_cast<const float4*>(in + (size_t)v2 * C1 + l * 4);
        float4 x3 = *reinterpret_cast<const float4*>(in + (size_t)v3 * C1 + l * 4);
        if (WS) ws += w0 + w1 + w2 + w3;
        acc.x = fmaf(w0, x0.x, acc.x); acc.y = fmaf(w0, x0.y, acc.y);
        acc.z = fmaf(w0, x0.z, acc.z); acc.w = fmaf(w0, x0.w, acc.w);
        acc.x = fmaf(w1, x1.x, acc.x); acc.y = fmaf(w1, x1.y, acc.y);
        acc.z = fmaf(w1, x1.z, acc.z); acc.w = fmaf(w1, x1.w, acc.w);
        acc.x = fmaf(w2, x2.x, acc.x); acc.y = fmaf(w2, x2.y, acc.y);
        acc.z = fmaf(w2, x2.z, acc.z); acc.w = fmaf(w2, x2.w, acc.w);
        acc.x = fmaf(w3, x3.x, acc.x); acc.y = fmaf(w3, x3.y, acc.y);
        acc.z = fmaf(w3, x3.z, acc.z); acc.w = fmaf(w3, x3.w, acc.w);
    }
    for (; j < n; j += 2) {
        int v = inc_v[st + j];
        float w = dv_isqrt[v];
        float4 x = *reinterpret_cast<const float4*>(in + (size_t)v * C1 + l * 4);
        if (WS) ws += w;
        acc.x = fmaf(w, x.x, acc.x); acc.y = fmaf(w, x.y, acc.y);
        acc.z = fmaf(w, x.z, acc.z); acc.w = fmaf(w, x.w, acc.w);
    }
    acc.x += __shfl_xor(acc.x, 32);
    acc.y += __shfl_xor(acc.y, 32);
    acc.z += __shfl_xor(acc.z, 32);
    acc.w += __shfl_xor(acc.w, 32);
    if (WS) ws += __shfl_xor(ws, 32);   // uniform-path shfl, before divergence
    if (half == 0) {
        float sc = de_inv[gw];
        float4 o = {acc.x * sc, acc.y * sc, acc.z * sc, acc.w * sc};
        *reinterpret_cast<float4*>(out + (size_t)gw * C1 + l * 4) = o;
        if (WS && l == 0) se[gw] = ws * sc;
    }
}

// Out[v][c] = dv_isqrt[v] * sum_{e in csr[v]} In[e][c]
// SV: svec[v] = dv_isqrt[v] * sum_{e in csr[v]} se[e]
template <bool SV>
__global__ void k_gather_nodes(const int* __restrict__ noff, const int* __restrict__ dv_cnt,
                               const int* __restrict__ csr_e, const float* __restrict__ in,
                               const float* __restrict__ dv_isqrt, float* __restrict__ out,
                               const float* __restrict__ se, float* __restrict__ svec) {
    int gw = (blockIdx.x * blockDim.x + threadIdx.x) >> 6;
    int lane = threadIdx.x & 63;
    if (gw >= N_NODES) return;
    int half = lane >> 5;
    int l = lane & 31;
    int st = noff[gw], n = dv_cnt[gw];
    float4 acc = {0.f, 0.f, 0.f, 0.f};
    float sv = 0.f;
    int j = half;
    for (; j + 6 < n; j += 8) {
        int e0 = csr_e[st + j],     e1 = csr_e[st + j + 2];
        int e2 = csr_e[st + j + 4], e3 = csr_e[st + j + 6];
        float4 y0 = *reinterpret_cast<const float4*>(in + (size_t)e0 * C1 + l * 4);
        float4 y1 = *reinterpret_cast<const float4*>(in + (size_t)e1 * C1 + l * 4);
        float4 y2 = *reinterpret_cast<const float4*>(in + (size_t)e2 * C1 + l * 4);
        float4 y3 = *reinterpret_cast<const float4*>(in + (size_t)e3 * C1 + l * 4);
        if (SV) sv += se[e0] + se[e1] + se[e2] + se[e3];   // broadcast loads
        acc.x += y0.x + y1.x + y2.x + y3.x;
        acc.y += y0.y + y1.y + y2.y + y3.y;
        acc.z += y0.z + y1.z + y2.z + y3.z;
        acc.w += y0.w + y1.w + y2.w + y3.w;
    }
    for (; j < n; j += 2) {
        int e = csr_e[st + j];
        float4 y = *reinterpret_cast<const float4*>(in + (size_t)e * C1 + l * 4);
        if (SV) sv += se[e];
        acc.x += y.x; acc.y += y.y; acc.z += y.z; acc.w += y.w;
    }
    acc.x += __shfl_xor(acc.x, 32);
    acc.y += __shfl_xor(acc.y, 32);
    acc.z += __shfl_xor(acc.z, 32);
    acc.w += __shfl_xor(acc.w, 32);
    if (SV) sv += __shfl_xor(sv, 32);   // uniform-path shfl, before divergence
    if (half == 0) {
        float sc = dv_isqrt[gw];
        float4 o = {acc.x * sc, acc.y * sc, acc.z * sc, acc.w * sc};
        *reinterpret_cast<float4*>(out + (size_t)gw * C1 + l * 4) = o;
        if (SV && l == 0) svec[gw] = sv * sc;
    }
}

// Final node gather fused with the fc head:
//   z[v][c] = relu(dv_isqrt[v] * sum_e In[e][c])   (never materialized)
//   t[v]    = sum_c z[v][c] * fcW[c]
__global__ void k_gather_nodes_fc(const int* __restrict__ noff, const int* __restrict__ dv_cnt,
                                  const int* __restrict__ csr_e, const float* __restrict__ in,
                                  const float* __restrict__ dv_isqrt, const float* __restrict__ fcW,
                                  float* __restrict__ t) {
    int gw = (blockIdx.x * blockDim.x + threadIdx.x) >> 6;
    int lane = threadIdx.x & 63;
    if (gw >= N_NODES) return;
    int half = lane >> 5;
    int l = lane & 31;
    int st = noff[gw], n = dv_cnt[gw];
    float4 acc = {0.f, 0.f, 0.f, 0.f};
    int j = half;
    for (; j + 6 < n; j += 8) {
        int e0 = csr_e[st + j],     e1 = csr_e[st + j + 2];
        int e2 = csr_e[st + j + 4], e3 = csr_e[st + j + 6];
        float4 y0 = *reinterpret_cast<const float4*>(in + (size_t)e0 * C1 + l * 4);
        float4 y1 = *reinterpret_cast<const float4*>(in + (size_t)e1 * C1 + l * 4);
        float4 y2 = *reinterpret_cast<const float4*>(in + (size_t)e2 * C1 + l * 4);
        float4 y3 = *reinterpret_cast<const float4*>(in + (size_t)e3 * C1 + l * 4);
        acc.x += y0.x + y1.x + y2.x + y3.x;
        acc.y += y0.y + y1.y + y2.y + y3.y;
        acc.z += y0.z + y1.z + y2.z + y3.z;
        acc.w += y0.w + y1.w + y2.w + y3.w;
    }
    for (; j < n; j += 2) {
        int e = csr_e[st + j];
        float4 y = *reinterpret_cast<const float4*>(in + (size_t)e * C1 + l * 4);
        acc.x += y.x; acc.y += y.y; acc.z += y.z; acc.w += y.w;
    }
    acc.x += __shfl_xor(acc.x, 32);
    acc.y += __shfl_xor(acc.y, 32);
    acc.z += __shfl_xor(acc.z, 32);
    acc.w += __shfl_xor(acc.w, 32);
    float sc = dv_isqrt[gw];
    float4 w = *reinterpret_cast<const float4*>(fcW + l * 4);
    float p = fmaxf(acc.x * sc, 0.f) * w.x + fmaxf(acc.y * sc, 0.f) * w.y +
              fmaxf(acc.z * sc, 0.f) * w.z + fmaxf(acc.w * sc, 0.f) * w.w;
#pragma unroll
    for (int off = 16; off > 0; off >>= 1) p += __shfl_xor(p, off);
    if (lane == 0) t[gw] = p;
}

// ---------------- fp32 tiled GEMM, 128x128 tile, 8x8/thread ----------------
// (no fp32 MFMA on CDNA4 — vector FMA; 8x8/thread gives 2 flop/LDS-byte so
//  the kernel is FMA-issue-bound, not LDS-BW-bound like a 4x4 mapping)
// C[M,N] = A[M,K] @ B[K,N], epilogue:
//   EPI==1: relu(acc + svec[row]*bias[col])
//   EPI==2: acc + bias[col]
template <int K, int EPI>
__global__ __launch_bounds__(256, 2) void k_gemm(const float* __restrict__ A,
                                                 const float* __restrict__ B,
                                                 const float* __restrict__ bias,
                                                 const float* __restrict__ svec,
                                                 float* __restrict__ C, int M, int N) {
    __shared__ float As[16][132];   // [k][m], row stride 528 B (16B-aligned)
    __shared__ float Bs[16][132];   // [k][n]
    const int tid = threadIdx.x;
    const int bm = blockIdx.y * 128;
    const int bn = blockIdx.x * 128;
    const int rm = (tid >> 4) * 4;    // 0..60
    const int cn = (tid & 15) * 4;    // 0..60
    float acc[8][8] = {};

    const int arow = tid >> 2;        // 0..63   (A tile: 128 rows x 16 k)
    const int akc  = (tid & 3) * 4;   // 0,4,8,12
    const int brow = tid >> 5;        // 0..7    (B tile: 16 k x 128 n)
    const int bcol = (tid & 31) * 4;  // 0..124

    for (int kk = 0; kk < K; kk += 16) {
#pragma unroll
        for (int h = 0; h < 2; ++h) {
            int row = bm + arow + h * 64;
            float4 a = {0.f, 0.f, 0.f, 0.f};
            if (row < M) a = *reinterpret_cast<const float4*>(A + (size_t)row * K + kk + akc);
            As[akc + 0][arow + h * 64] = a.x;
            As[akc + 1][arow + h * 64] = a.y;
            As[akc + 2][arow + h * 64] = a.z;
            As[akc + 3][arow + h * 64] = a.w;
        }
#pragma unroll
        for (int h = 0; h < 2; ++h) {
            int kr = brow + h * 8;
            *reinterpret_cast<float4*>(&Bs[kr][bcol]) =
                *reinterpret_cast<const float4*>(B + (size_t)(kk + kr) * N + bn + bcol);
        }
        __syncthreads();
#pragma unroll
        for (int k = 0; k < 16; ++k) {
            float4 a0 = *reinterpret_cast<const float4*>(&As[k][rm]);
            float4 a1 = *reinterpret_cast<const float4*>(&As[k][64 + rm]);
            float4 b0 = *reinterpret_cast<const float4*>(&Bs[k][cn]);
            float4 b1 = *reinterpret_cast<const float4*>(&Bs[k][64 + cn]);
            float av[8] = {a0.x, a0.y, a0.z, a0.w, a1.x, a1.y, a1.z, a1.w};
            float bv[8] = {b0.x, b0.y, b0.z, b0.w, b1.x, b1.y, b1.z, b1.w};
#pragma unroll
            for (int i = 0; i < 8; ++i)
#pragma unroll
                for (int j = 0; j < 8; ++j)
                    acc[i][j] = fmaf(av[i], bv[j], acc[i][j]);
        }
        __syncthreads();
    }

    const float4 bv0 = *reinterpret_cast<const float4*>(bias + bn + cn);
    const float4 bv1 = *reinterpret_cast<const float4*>(bias + bn + 64 + cn);
    const float bb0[4] = {bv0.x, bv0.y, bv0.z, bv0.w};
    const float bb1[4] = {bv1.x, bv1.y, bv1.z, bv1.w};
#pragma unroll
    for (int i = 0; i < 8; ++i) {
        int row = bm + ((i < 4) ? (rm + i) : (64 + rm + i - 4));
        if (row >= M) continue;
        float s = (EPI == 1) ? svec[row] : 0.f;
        float4 o0, o1;
        float* p0 = &o0.x; float* p1 = &o1.x;
#pragma unroll
        for (int j = 0; j < 4; ++j) {
            float x0, x1;
            if (EPI == 1) {
                x0 = fmaxf(fmaf(s, bb0[j], acc[i][j]), 0.f);
                x1 = fmaxf(fmaf(s, bb1[j], acc[i][j + 4]), 0.f);
            } else {
                x0 = acc[i][j] + bb0[j];
                x1 = acc[i][j + 4] + bb1[j];
            }
            p0[j] = x0; p1[j] = x1;
        }
        *reinterpret_cast<float4*>(C + (size_t)row * N + bn + cn) = o0;
        *reinterpret_cast<float4*>(C + (size_t)row * N + bn + 64 + cn) = o1;
    }
}

// ---------------- link head ----------------

__global__ void k_link(const int* __restrict__ link, const float* __restrict__ t,
                       const float* __restrict__ fcb, float* __restrict__ out) {
    int l = blockIdx.x * blockDim.x + threadIdx.x;
    if (l >= N_LINKS) return;
    int a = link[2 * l], b = link[2 * l + 1];
    float x = 0.5f * (t[a] + t[b]) + fcb[0];
    out[l] = 1.f / (1.f + expf(-x));
}

// ---------------- host ----------------

extern "C" void kernel_launch(void* const* d_in, const int* in_sizes, int n_in,
                              void* d_out, int out_size, void* d_ws, size_t ws_size,
                              hipStream_t stream) {
    const float* X    = (const float*)d_in[0];
    const float* W1   = (const float*)d_in[1];
    const float* b1   = (const float*)d_in[2];
    const float* W2   = (const float*)d_in[3];
    const float* b2   = (const float*)d_in[4];
    const float* fcW  = (const float*)d_in[5];
    const float* fcb  = (const float*)d_in[6];
    const int* inc_v  = (const int*)d_in[7];
    const int* inc_e  = (const int*)d_in[8];
    const int* link   = (const int*)d_in[9];
    float* out = (float*)d_out;

    size_t off = 0;
    auto carve = [&](size_t nbytes) -> void* {
        void* p = (char*)d_ws + off;
        off += (nbytes + 255) & ~(size_t)255;
        return p;
    };
    int* dv_cnt  = (int*)carve((size_t)N_NODES * 4);
    int* de_cnt  = (int*)carve((size_t)N_HEDGES * 4);
    int* hoff    = (int*)carve((size_t)N_HEDGES * 4);
    int* noff    = (int*)carve((size_t)N_NODES * 4);
    int* cursor  = (int*)carve((size_t)N_NODES * 4);
    int* bsum    = (int*)carve(512 * 4);
    float* dv_isqrt = (float*)carve((size_t)N_NODES * 4);
    float* de_inv   = (float*)carve((size_t)N_HEDGES * 4);
    float* se    = (float*)carve((size_t)N_HEDGES * 4);
    float* svec  = (float*)carve((size_t)N_NODES * 4);
    float* tvec  = (float*)carve((size_t)N_NODES * 4);
    int* csr_e   = (int*)carve((size_t)N_INC * 4);
    // Workspace aliasing (peak ~168 MB instead of ~218 MB):
    //   R0 (102.4 MB) holds, in stream order:
    //     Ye(layer1) [first 51.2 MB]  -> dead before gemm1
    //     H = smooth(X)@W1 output (all 102.4 MB) -> dead after gemm2
    //     Ye(layer2) [first 51.2 MB]  -> written after gemm2
    //   Xs (51.2 MB) is separate: live into gemm1 (input) while H is written.
    float* R0    = (float*)carve((size_t)N_NODES * 256 * 4);   // 102.4 MB
    float* Xs    = (float*)carve((size_t)N_NODES * C1 * 4);    // 51.2 MB
    float* Ye    = R0;        // 51.2 MB window, lifetimes disjoint from H
    float* H     = R0;        // full 102.4 MB

    // Guard: if the harness workspace is smaller than our carve total, bail
    // cleanly (validation will fail attributably) instead of corrupting memory.
    if (off > ws_size) return;

    // structure
    k_init<<<SCAN_NB, 256, 0, stream>>>(dv_cnt, de_cnt, hoff);
    k_count<<<N_INC / 256, 256, 0, stream>>>(inc_v, inc_e, dv_cnt, de_cnt, hoff);
    k_transform<<<SCAN_NB, 256, 0, stream>>>(dv_cnt, de_cnt, dv_isqrt, de_inv);
    k_scan_blocksum<<<SCAN_NB, 256, 0, stream>>>(dv_cnt, bsum);
    k_scan_bsum<<<1, 512, 0, stream>>>(bsum);
    k_scan_write<<<SCAN_NB, 256, 0, stream>>>(dv_cnt, bsum, noff, cursor);
    k_fill_csr<<<N_INC / 256, 256, 0, stream>>>(inc_v, inc_e, cursor, csr_e);

    // layer 1: h = relu(smooth(X) @ W1 + s*b1)   [smooth commutes with channel
    // matmul]; s = smooth(ones) is fused into the two gathers (WS/SV=true):
    // edge pass also emits se[], node pass also emits svec[].
    k_gather_edges<true><<<25000, 256, 0, stream>>>(hoff, de_cnt, inc_v, X, dv_isqrt, de_inv, Ye, se);
    k_gather_nodes<true><<<25000, 256, 0, stream>>>(noff, dv_cnt, csr_e, Ye, dv_isqrt, Xs, se, svec);
    k_gemm<128, 1><<<dim3(2, (N_NODES + 127) / 128), 256, 0, stream>>>(Xs, W1, b1, svec, H, N_NODES, 256);

    // layer 2: z = relu(smooth(H @ W2 + b2)); fc-dot fused into final gather
    k_gemm<256, 2><<<dim3(1, (N_NODES + 127) / 128), 256, 0, stream>>>(H, W2, b2, nullptr, Xs, N_NODES, 128);
    k_gather_edges<false><<<25000, 256, 0, stream>>>(hoff, de_cnt, inc_v, Xs, dv_isqrt, de_inv, Ye, nullptr);
    k_gather_nodes_fc<<<25000, 256, 0, stream>>>(noff, dv_cnt, csr_e, Ye, dv_isqrt, fcW, tvec);

    // out = sigmoid(0.5*(t[a]+t[b]) + fcb)
    k_link<<<N_LINKS / 256, 256, 0, stream>>>(link, tvec, fcb, out);
}

// Round 12
// 1258.125 us; speedup vs baseline: 1.3989x; 1.3989x over previous
//
#include <hip/hip_runtime.h>
#include <math.h>

#define N_NODES  100000
#define N_HEDGES 100000
#define N_INC    3200000
#define N_LINKS  262144

constexpr int C1 = 128;     // smooth channel width
constexpr int NBKT = 782;   // ceil(N_NODES / 128); bucket b covers nodes [b*128, b*128+128)
constexpr int RSV_STRIDE = 16;   // pad bucket counters to 64B lines (atomics write through to fabric)
constexpr int BCAP = 8192;       // bucket capacity; mean load 4096, sigma ~64 -> 64-sigma margin
constexpr int P1_NB = 400;       // phase-1 blocks; N_INC = 400 * 8000 exactly
constexpr int P1_CHUNK = 8000;

// ---------------- structure: no device-scope atomics on the hot path ----------------

__global__ void k_init2(int* hoff, int* hend, int* rsv) {
    int i = blockIdx.x * blockDim.x + threadIdx.x;
    if (i < N_HEDGES) { hoff[i] = 0; hend[i] = 0; }
    if (i < NBKT * RSV_STRIDE) rsv[i] = 0;
}

// inc_e is sorted: boundary detection gives segment extents without atomics.
__global__ void k_boundary(const int* __restrict__ inc_e, int* __restrict__ hoff,
                           int* __restrict__ hend) {
    int i = blockIdx.x * blockDim.x + threadIdx.x;
    if (i >= N_INC) return;
    int e = inc_e[i];
    if (i == 0 || inc_e[i - 1] != e) hoff[e] = i;
    if (i == N_INC - 1 || inc_e[i + 1] != e) hend[e] = i + 1;
}

__global__ void k_transform_e(const int* __restrict__ hoff, const int* __restrict__ hend,
                              int* __restrict__ de_cnt, float* __restrict__ de_inv) {
    int e = blockIdx.x * blockDim.x + threadIdx.x;
    if (e >= N_HEDGES) return;
    int d = hend[e] - hoff[e];            // absent hyperedge: 0 - 0 = 0
    de_cnt[e] = d;
    de_inv[e] = (d > 0) ? 1.0f / (float)d : 0.0f;
}

// Phase 1: bucket (v,e) pairs by v>>7. Per-block LDS histogram -> ONE global
// atomic per (block,bucket) on a 64B-padded counter (313K atomics total vs
// 6.4M before) -> scatter pairs into fixed-capacity bucket regions.
__global__ __launch_bounds__(256) void k_phase1(const int* __restrict__ inc_v,
                                                const int* __restrict__ inc_e,
                                                int* __restrict__ rsv,
                                                uint2* __restrict__ pairs) {
    __shared__ int hist[NBKT];
    __shared__ int base[NBKT];
    const int t = threadIdx.x;
    const int start = blockIdx.x * P1_CHUNK;
    for (int b = t; b < NBKT; b += 256) hist[b] = 0;
    __syncthreads();
    for (int i = start + t; i < start + P1_CHUNK; i += 256)
        atomicAdd(&hist[inc_v[i] >> 7], 1);               // LDS atomic (workgroup scope)
    __syncthreads();
    for (int b = t; b < NBKT; b += 256) {
        int c = hist[b];
        base[b] = (c > 0) ? atomicAdd(&rsv[b * RSV_STRIDE], c) : 0;  // one per (block,bucket)
        hist[b] = 0;                                       // reuse as local cursor
    }
    __syncthreads();
    for (int i = start + t; i < start + P1_CHUNK; i += 256) {
        int v = inc_v[i];
        int e = inc_e[i];
        int b = v >> 7;
        int r = base[b] + atomicAdd(&hist[b], 1);
        if (r < BCAP)                                      // 64-sigma guard; never triggers
            pairs[(size_t)b * BCAP + r] = make_uint2((unsigned)v, (unsigned)e);
    }
}

// Exclusive prefix over the 782 bucket sizes -> dense CSR base per bucket.
__global__ void k_scan_buckets(const int* __restrict__ rsv, int* __restrict__ bucket_base) {
    __shared__ int s[1024];
    int t = threadIdx.x;
    int own = (t < NBKT) ? rsv[t * RSV_STRIDE] : 0;
    s[t] = own;
    __syncthreads();
    for (int off = 1; off < 1024; off <<= 1) {
        int v = (t >= off) ? s[t - off] : 0;
        __syncthreads();
        s[t] += v;
        __syncthreads();
    }
    if (t < NBKT) bucket_base[t] = s[t] - own;
}

// Phase 2: one block per bucket. 128-bin LDS counting sort -> dense coalesced
// csr_e window + dv_cnt / dv_isqrt / noff for the bucket's 128 nodes.
__global__ __launch_bounds__(256) void k_phase2(const int* __restrict__ rsv,
                                                const int* __restrict__ bucket_base,
                                                const uint2* __restrict__ pairs,
                                                int* __restrict__ csr_e,
                                                int* __restrict__ dv_cnt,
                                                float* __restrict__ dv_isqrt,
                                                int* __restrict__ noff) {
    __shared__ int cnt[128];
    __shared__ int pfx[128];
    __shared__ int curs[128];
    const int t = threadIdx.x;
    const int b = blockIdx.x;
    int sz = rsv[b * RSV_STRIDE];
    if (sz > BCAP) sz = BCAP;
    const int gbase = bucket_base[b];
    const uint2* mp = pairs + (size_t)b * BCAP;
    if (t < 128) cnt[t] = 0;
    __syncthreads();
    for (int i = t; i < sz; i += 256)
        atomicAdd(&cnt[mp[i].x & 127], 1);
    __syncthreads();
    if (t < 128) pfx[t] = cnt[t];
    __syncthreads();
    for (int off = 1; off < 128; off <<= 1) {      // inclusive Hillis-Steele on 128
        int v = (t < 128 && t >= off) ? pfx[t - off] : 0;
        __syncthreads();
        if (t < 128) pfx[t] += v;
        __syncthreads();
    }
    if (t < 128) {
        int excl = pfx[t] - cnt[t];
        curs[t] = excl;
        int v = (b << 7) + t;
        if (v < N_NODES) {
            int c = cnt[t];
            dv_cnt[v] = c;
            dv_isqrt[v] = (c > 0) ? 1.0f / sqrtf((float)c) : 0.0f;
            noff[v] = gbase + excl;
        }
    }
    __syncthreads();
    for (int i = t; i < sz; i += 256) {
        uint2 p = mp[i];
        int r = atomicAdd(&curs[p.x & 127], 1);    // LDS atomic; order within node arbitrary
        csr_e[gbase + r] = (int)p.y;
    }
}

// ---------------- feature segment sums ----------------
// Wave-per-segment; two 32-lane halves (even/odd incidences), float4/lane.
// Layer-1 instantiations (WS/SV) fuse s = smooth(ones) side outputs.

template <bool WS>
__global__ void k_gather_edges(const int* __restrict__ hoff, const int* __restrict__ de_cnt,
                               const int* __restrict__ inc_v, const float* __restrict__ in,
                               const float* __restrict__ dv_isqrt, const float* __restrict__ de_inv,
                               float* __restrict__ out, float* __restrict__ se) {
    int gw = (blockIdx.x * blockDim.x + threadIdx.x) >> 6;
    int lane = threadIdx.x & 63;
    if (gw >= N_HEDGES) return;
    int half = lane >> 5;
    int l = lane & 31;
    int st = hoff[gw], n = de_cnt[gw];
    float4 acc = {0.f, 0.f, 0.f, 0.f};
    float ws = 0.f;
    int j = half;
    for (; j + 6 < n; j += 8) {
        int v0 = inc_v[st + j],     v1 = inc_v[st + j + 2];
        int v2 = inc_v[st + j + 4], v3 = inc_v[st + j + 6];
        float w0 = dv_isqrt[v0], w1 = dv_isqrt[v1];
        float w2 = dv_isqrt[v2], w3 = dv_isqrt[v3];
        float4 x0 = *reinterpret_cast<const float4*>(in + (size_t)v0 * C1 + l * 4);
        float4 x1 = *reinterpret_cast<const float4*>(in + (size_t)v1 * C1 + l * 4);
        float4 x2 = *reinterpret_cast<const float4*>(in + (size_t)v2 * C1 + l * 4);
        float4 x3 = *reinterpret_cast<const float4*>(in + (size_t)v3 * C1 + l * 4);
        if (WS) ws += w0 + w1 + w2 + w3;
        acc.x = fmaf(w0, x0.x, acc.x); acc.y = fmaf(w0, x0.y, acc.y);
        acc.z = fmaf(w0, x0.z, acc.z); acc.w = fmaf(w0, x0.w, acc.w);
        acc.x = fmaf(w1, x1.x, acc.x); acc.y = fmaf(w1, x1.y, acc.y);
        acc.z = fmaf(w1, x1.z, acc.z); acc.w = fmaf(w1, x1.w, acc.w);
        acc.x = fmaf(w2, x2.x, acc.x); acc.y = fmaf(w2, x2.y, acc.y);
        acc.z = fmaf(w2, x2.z, acc.z); acc.w = fmaf(w2, x2.w, acc.w);
        acc.x = fmaf(w3, x3.x, acc.x); acc.y = fmaf(w3, x3.y, acc.y);
        acc.z = fmaf(w3, x3.z, acc.z); acc.w = fmaf(w3, x3.w, acc.w);
    }
    for (; j < n; j += 2) {
        int v = inc_v[st + j];
        float w = dv_isqrt[v];
        float4 x = *reinterpret_cast<const float4*>(in + (size_t)v * C1 + l * 4);
        if (WS) ws += w;
        acc.x = fmaf(w, x.x, acc.x); acc.y = fmaf(w, x.y, acc.y);
        acc.z = fmaf(w, x.z, acc.z); acc.w = fmaf(w, x.w, acc.w);
    }
    acc.x += __shfl_xor(acc.x, 32);
    acc.y += __shfl_xor(acc.y, 32);
    acc.z += __shfl_xor(acc.z, 32);
    acc.w += __shfl_xor(acc.w, 32);
    if (WS) ws += __shfl_xor(ws, 32);
    if (half == 0) {
        float sc = de_inv[gw];
        float4 o = {acc.x * sc, acc.y * sc, acc.z * sc, acc.w * sc};
        *reinterpret_cast<float4*>(out + (size_t)gw * C1 + l * 4) = o;
        if (WS && l == 0) se[gw] = ws * sc;
    }
}

template <bool SV>
__global__ void k_gather_nodes(const int* __restrict__ noff, const int* __restrict__ dv_cnt,
                               const int* __restrict__ csr_e, const float* __restrict__ in,
                               const float* __restrict__ dv_isqrt, float* __restrict__ out,
                               const float* __restrict__ se, float* __restrict__ svec) {
    int gw = (blockIdx.x * blockDim.x + threadIdx.x) >> 6;
    int lane = threadIdx.x & 63;
    if (gw >= N_NODES) return;
    int half = lane >> 5;
    int l = lane & 31;
    int st = noff[gw], n = dv_cnt[gw];
    float4 acc = {0.f, 0.f, 0.f, 0.f};
    float sv = 0.f;
    int j = half;
    for (; j + 6 < n; j += 8) {
        int e0 = csr_e[st + j],     e1 = csr_e[st + j + 2];
        int e2 = csr_e[st + j + 4], e3 = csr_e[st + j + 6];
        float4 y0 = *reinterpret_cast<const float4*>(in + (size_t)e0 * C1 + l * 4);
        float4 y1 = *reinterpret_cast<const float4*>(in + (size_t)e1 * C1 + l * 4);
        float4 y2 = *reinterpret_cast<const float4*>(in + (size_t)e2 * C1 + l * 4);
        float4 y3 = *reinterpret_cast<const float4*>(in + (size_t)e3 * C1 + l * 4);
        if (SV) sv += se[e0] + se[e1] + se[e2] + se[e3];
        acc.x += y0.x + y1.x + y2.x + y3.x;
        acc.y += y0.y + y1.y + y2.y + y3.y;
        acc.z += y0.z + y1.z + y2.z + y3.z;
        acc.w += y0.w + y1.w + y2.w + y3.w;
    }
    for (; j < n; j += 2) {
        int e = csr_e[st + j];
        float4 y = *reinterpret_cast<const float4*>(in + (size_t)e * C1 + l * 4);
        if (SV) sv += se[e];
        acc.x += y.x; acc.y += y.y; acc.z += y.z; acc.w += y.w;
    }
    acc.x += __shfl_xor(acc.x, 32);
    acc.y += __shfl_xor(acc.y, 32);
    acc.z += __shfl_xor(acc.z, 32);
    acc.w += __shfl_xor(acc.w, 32);
    if (SV) sv += __shfl_xor(sv, 32);
    if (half == 0) {
        float sc = dv_isqrt[gw];
        float4 o = {acc.x * sc, acc.y * sc, acc.z * sc, acc.w * sc};
        *reinterpret_cast<float4*>(out + (size_t)gw * C1 + l * 4) = o;
        if (SV && l == 0) svec[gw] = sv * sc;
    }
}

__global__ void k_gather_nodes_fc(const int* __restrict__ noff, const int* __restrict__ dv_cnt,
                                  const int* __restrict__ csr_e, const float* __restrict__ in,
                                  const float* __restrict__ dv_isqrt, const float* __restrict__ fcW,
                                  float* __restrict__ t) {
    int gw = (blockIdx.x * blockDim.x + threadIdx.x) >> 6;
    int lane = threadIdx.x & 63;
    if (gw >= N_NODES) return;
    int half = lane >> 5;
    int l = lane & 31;
    int st = noff[gw], n = dv_cnt[gw];
    float4 acc = {0.f, 0.f, 0.f, 0.f};
    int j = half;
    for (; j + 6 < n; j += 8) {
        int e0 = csr_e[st + j],     e1 = csr_e[st + j + 2];
        int e2 = csr_e[st + j + 4], e3 = csr_e[st + j + 6];
        float4 y0 = *reinterpret_cast<const float4*>(in + (size_t)e0 * C1 + l * 4);
        float4 y1 = *reinterpret_cast<const float4*>(in + (size_t)e1 * C1 + l * 4);
        float4 y2 = *reinterpret_cast<const float4*>(in + (size_t)e2 * C1 + l * 4);
        float4 y3 = *reinterpret_cast<const float4*>(in + (size_t)e3 * C1 + l * 4);
        acc.x += y0.x + y1.x + y2.x + y3.x;
        acc.y += y0.y + y1.y + y2.y + y3.y;
        acc.z += y0.z + y1.z + y2.z + y3.z;
        acc.w += y0.w + y1.w + y2.w + y3.w;
    }
    for (; j < n; j += 2) {
        int e = csr_e[st + j];
        float4 y = *reinterpret_cast<const float4*>(in + (size_t)e * C1 + l * 4);
        acc.x += y.x; acc.y += y.y; acc.z += y.z; acc.w += y.w;
    }
    acc.x += __shfl_xor(acc.x, 32);
    acc.y += __shfl_xor(acc.y, 32);
    acc.z += __shfl_xor(acc.z, 32);
    acc.w += __shfl_xor(acc.w, 32);
    float sc = dv_isqrt[gw];
    float4 w = *reinterpret_cast<const float4*>(fcW + l * 4);
    float p = fmaxf(acc.x * sc, 0.f) * w.x + fmaxf(acc.y * sc, 0.f) * w.y +
              fmaxf(acc.z * sc, 0.f) * w.z + fmaxf(acc.w * sc, 0.f) * w.w;
#pragma unroll
    for (int off = 16; off > 0; off >>= 1) p += __shfl_xor(p, off);
    if (lane == 0) t[gw] = p;
}

// ---------------- fp32 tiled GEMM, 128x128 tile, 8x8/thread ----------------
template <int K, int EPI>
__global__ __launch_bounds__(256, 2) void k_gemm(const float* __restrict__ A,
                                                 const float* __restrict__ B,
                                                 const float* __restrict__ bias,
                                                 const float* __restrict__ svec,
                                                 float* __restrict__ C, int M, int N) {
    __shared__ float As[16][132];
    __shared__ float Bs[16][132];
    const int tid = threadIdx.x;
    const int bm = blockIdx.y * 128;
    const int bn = blockIdx.x * 128;
    const int rm = (tid >> 4) * 4;
    const int cn = (tid & 15) * 4;
    float acc[8][8] = {};

    const int arow = tid >> 2;
    const int akc  = (tid & 3) * 4;
    const int brow = tid >> 5;
    const int bcol = (tid & 31) * 4;

    for (int kk = 0; kk < K; kk += 16) {
#pragma unroll
        for (int h = 0; h < 2; ++h) {
            int row = bm + arow + h * 64;
            float4 a = {0.f, 0.f, 0.f, 0.f};
            if (row < M) a = *reinterpret_cast<const float4*>(A + (size_t)row * K + kk + akc);
            As[akc + 0][arow + h * 64] = a.x;
            As[akc + 1][arow + h * 64] = a.y;
            As[akc + 2][arow + h * 64] = a.z;
            As[akc + 3][arow + h * 64] = a.w;
        }
#pragma unroll
        for (int h = 0; h < 2; ++h) {
            int kr = brow + h * 8;
            *reinterpret_cast<float4*>(&Bs[kr][bcol]) =
                *reinterpret_cast<const float4*>(B + (size_t)(kk + kr) * N + bn + bcol);
        }
        __syncthreads();
#pragma unroll
        for (int k = 0; k < 16; ++k) {
            float4 a0 = *reinterpret_cast<const float4*>(&As[k][rm]);
            float4 a1 = *reinterpret_cast<const float4*>(&As[k][64 + rm]);
            float4 b0 = *reinterpret_cast<const float4*>(&Bs[k][cn]);
            float4 b1 = *reinterpret_cast<const float4*>(&Bs[k][64 + cn]);
            float av[8] = {a0.x, a0.y, a0.z, a0.w, a1.x, a1.y, a1.z, a1.w};
            float bv[8] = {b0.x, b0.y, b0.z, b0.w, b1.x, b1.y, b1.z, b1.w};
#pragma unroll
            for (int i = 0; i < 8; ++i)
#pragma unroll
                for (int j = 0; j < 8; ++j)
                    acc[i][j] = fmaf(av[i], bv[j], acc[i][j]);
        }
        __syncthreads();
    }

    const float4 bv0 = *reinterpret_cast<const float4*>(bias + bn + cn);
    const float4 bv1 = *reinterpret_cast<const float4*>(bias + bn + 64 + cn);
    const float bb0[4] = {bv0.x, bv0.y, bv0.z, bv0.w};
    const float bb1[4] = {bv1.x, bv1.y, bv1.z, bv1.w};
#pragma unroll
    for (int i = 0; i < 8; ++i) {
        int row = bm + ((i < 4) ? (rm + i) : (64 + rm + i - 4));
        if (row >= M) continue;
        float s = (EPI == 1) ? svec[row] : 0.f;
        float4 o0, o1;
        float* p0 = &o0.x; float* p1 = &o1.x;
#pragma unroll
        for (int j = 0; j < 4; ++j) {
            float x0, x1;
            if (EPI == 1) {
                x0 = fmaxf(fmaf(s, bb0[j], acc[i][j]), 0.f);
                x1 = fmaxf(fmaf(s, bb1[j], acc[i][j + 4]), 0.f);
            } else {
                x0 = acc[i][j] + bb0[j];
                x1 = acc[i][j + 4] + bb1[j];
            }
            p0[j] = x0; p1[j] = x1;
        }
        *reinterpret_cast<float4*>(C + (size_t)row * N + bn + cn) = o0;
        *reinterpret_cast<float4*>(C + (size_t)row * N + bn + 64 + cn) = o1;
    }
}

// ---------------- link head ----------------

__global__ void k_link(const int* __restrict__ link, const float* __restrict__ t,
                       const float* __restrict__ fcb, float* __restrict__ out) {
    int l = blockIdx.x * blockDim.x + threadIdx.x;
    if (l >= N_LINKS) return;
    int a = link[2 * l], b = link[2 * l + 1];
    float x = 0.5f * (t[a] + t[b]) + fcb[0];
    out[l] = 1.f / (1.f + expf(-x));
}

// ---------------- host ----------------

extern "C" void kernel_launch(void* const* d_in, const int* in_sizes, int n_in,
                              void* d_out, int out_size, void* d_ws, size_t ws_size,
                              hipStream_t stream) {
    const float* X    = (const float*)d_in[0];
    const float* W1   = (const float*)d_in[1];
    const float* b1   = (const float*)d_in[2];
    const float* W2   = (const float*)d_in[3];
    const float* b2   = (const float*)d_in[4];
    const float* fcW  = (const float*)d_in[5];
    const float* fcb  = (const float*)d_in[6];
    const int* inc_v  = (const int*)d_in[7];
    const int* inc_e  = (const int*)d_in[8];
    const int* link   = (const int*)d_in[9];
    float* out = (float*)d_out;

    size_t off = 0;
    auto carve = [&](size_t nbytes) -> void* {
        void* p = (char*)d_ws + off;
        off += (nbytes + 255) & ~(size_t)255;
        return p;
    };
    int* hoff    = (int*)carve((size_t)N_HEDGES * 4);
    int* hend    = (int*)carve((size_t)N_HEDGES * 4);
    int* de_cnt  = (int*)carve((size_t)N_HEDGES * 4);
    int* dv_cnt  = (int*)carve((size_t)N_NODES * 4);
    int* noff    = (int*)carve((size_t)N_NODES * 4);
    int* rsv     = (int*)carve((size_t)NBKT * RSV_STRIDE * 4);
    int* bucket_base = (int*)carve((size_t)NBKT * 4);
    float* dv_isqrt = (float*)carve((size_t)N_NODES * 4);
    float* de_inv   = (float*)carve((size_t)N_HEDGES * 4);
    float* se    = (float*)carve((size_t)N_HEDGES * 4);
    float* svec  = (float*)carve((size_t)N_NODES * 4);
    float* tvec  = (float*)carve((size_t)N_NODES * 4);
    int* csr_e   = (int*)carve((size_t)N_INC * 4);
    // R0 (102.4 MB) time-shares, in stream order:
    //   pairs (51.2 MB, phase1 write -> phase2 read, dead before first gather)
    //   Ye(layer1) -> dead before gemm1 writes H
    //   H (full 102.4 MB) -> dead after gemm2
    //   Ye(layer2)
    float* R0    = (float*)carve((size_t)N_NODES * 256 * 4);   // 102.4 MB
    float* Xs    = (float*)carve((size_t)N_NODES * C1 * 4);    // 51.2 MB
    uint2* pairs = (uint2*)R0;   // NBKT * BCAP * 8B = 51.2 MB window
    float* Ye    = R0;
    float* H     = R0;

    if (off > ws_size) return;   // clean, attributable failure instead of OOB

    // structure (atomic-light): boundary extents + bucketed counting sort
    k_init2<<<(N_HEDGES + 255) / 256, 256, 0, stream>>>(hoff, hend, rsv);
    k_boundary<<<N_INC / 256, 256, 0, stream>>>(inc_e, hoff, hend);
    k_transform_e<<<(N_HEDGES + 255) / 256, 256, 0, stream>>>(hoff, hend, de_cnt, de_inv);
    k_phase1<<<P1_NB, 256, 0, stream>>>(inc_v, inc_e, rsv, pairs);
    k_scan_buckets<<<1, 1024, 0, stream>>>(rsv, bucket_base);
    k_phase2<<<NBKT, 256, 0, stream>>>(rsv, bucket_base, pairs, csr_e, dv_cnt, dv_isqrt, noff);

    // layer 1: h = relu(smooth(X) @ W1 + s*b1); s = smooth(ones) fused (WS/SV)
    k_gather_edges<true><<<25000, 256, 0, stream>>>(hoff, de_cnt, inc_v, X, dv_isqrt, de_inv, Ye, se);
    k_gather_nodes<true><<<25000, 256, 0, stream>>>(noff, dv_cnt, csr_e, Ye, dv_isqrt, Xs, se, svec);
    k_gemm<128, 1><<<dim3(2, (N_NODES + 127) / 128), 256, 0, stream>>>(Xs, W1, b1, svec, H, N_NODES, 256);

    // layer 2: z = relu(smooth(H @ W2 + b2)); fc-dot fused into final gather
    k_gemm<256, 2><<<dim3(1, (N_NODES + 127) / 128), 256, 0, stream>>>(H, W2, b2, nullptr, Xs, N_NODES, 128);
    k_gather_edges<false><<<25000, 256, 0, stream>>>(hoff, de_cnt, inc_v, Xs, dv_isqrt, de_inv, Ye, nullptr);
    k_gather_nodes_fc<<<25000, 256, 0, stream>>>(noff, dv_cnt, csr_e, Ye, dv_isqrt, fcW, tvec);

    // out = sigmoid(0.5*(t[a]+t[b]) + fcb)
    k_link<<<N_LINKS / 256, 256, 0, stream>>>(link, tvec, fcb, out);
}

// Round 13
// 880.624 us; speedup vs baseline: 1.9985x; 1.4287x over previous
//
#include <hip/hip_runtime.h>
#include <math.h>

#define N_NODES  100000
#define N_HEDGES 100000
#define N_INC    3200000
#define N_LINKS  262144

typedef unsigned short u16;

constexpr int C1 = 128;     // smooth channel width
constexpr int NBKT = 782;   // ceil(N_NODES / 128)
constexpr int RSV_STRIDE = 16;
constexpr int BCAP = 8192;
constexpr int P1_NB = 400;
constexpr int P1_CHUNK = 8000;

// bf16 <-> fp32 (exact up / RNE down)
__device__ __forceinline__ float4 b4f(ushort4 u) {
    float4 f;
    f.x = __uint_as_float(((unsigned)u.x) << 16);
    f.y = __uint_as_float(((unsigned)u.y) << 16);
    f.z = __uint_as_float(((unsigned)u.z) << 16);
    f.w = __uint_as_float(((unsigned)u.w) << 16);
    return f;
}
__device__ __forceinline__ u16 f2b(float f) {
    unsigned u = __float_as_uint(f);
    u += 0x7FFFu + ((u >> 16) & 1u);   // round-to-nearest-even
    return (u16)(u >> 16);
}

// ---------------- structure: atomic-light bucketed counting sort ----------------

__global__ void k_init2(int* hoff, int* hend, int* rsv) {
    int i = blockIdx.x * blockDim.x + threadIdx.x;
    if (i < N_HEDGES) { hoff[i] = 0; hend[i] = 0; }
    if (i < NBKT * RSV_STRIDE) rsv[i] = 0;
}

__global__ void k_boundary(const int* __restrict__ inc_e, int* __restrict__ hoff,
                           int* __restrict__ hend) {
    int i = blockIdx.x * blockDim.x + threadIdx.x;
    if (i >= N_INC) return;
    int e = inc_e[i];
    if (i == 0 || inc_e[i - 1] != e) hoff[e] = i;
    if (i == N_INC - 1 || inc_e[i + 1] != e) hend[e] = i + 1;
}

__global__ void k_transform_e(const int* __restrict__ hoff, const int* __restrict__ hend,
                              int* __restrict__ de_cnt, float* __restrict__ de_inv) {
    int e = blockIdx.x * blockDim.x + threadIdx.x;
    if (e >= N_HEDGES) return;
    int d = hend[e] - hoff[e];
    de_cnt[e] = d;
    de_inv[e] = (d > 0) ? 1.0f / (float)d : 0.0f;
}

__global__ __launch_bounds__(256) void k_phase1(const int* __restrict__ inc_v,
                                                const int* __restrict__ inc_e,
                                                int* __restrict__ rsv,
                                                uint2* __restrict__ pairs) {
    __shared__ int hist[NBKT];
    __shared__ int base[NBKT];
    const int t = threadIdx.x;
    const int start = blockIdx.x * P1_CHUNK;
    for (int b = t; b < NBKT; b += 256) hist[b] = 0;
    __syncthreads();
    for (int i = start + t; i < start + P1_CHUNK; i += 256)
        atomicAdd(&hist[inc_v[i] >> 7], 1);
    __syncthreads();
    for (int b = t; b < NBKT; b += 256) {
        int c = hist[b];
        base[b] = (c > 0) ? atomicAdd(&rsv[b * RSV_STRIDE], c) : 0;
        hist[b] = 0;
    }
    __syncthreads();
    for (int i = start + t; i < start + P1_CHUNK; i += 256) {
        int v = inc_v[i];
        int e = inc_e[i];
        int b = v >> 7;
        int r = base[b] + atomicAdd(&hist[b], 1);
        if (r < BCAP)
            pairs[(size_t)b * BCAP + r] = make_uint2((unsigned)v, (unsigned)e);
    }
}

__global__ void k_scan_buckets(const int* __restrict__ rsv, int* __restrict__ bucket_base) {
    __shared__ int s[1024];
    int t = threadIdx.x;
    int own = (t < NBKT) ? rsv[t * RSV_STRIDE] : 0;
    s[t] = own;
    __syncthreads();
    for (int off = 1; off < 1024; off <<= 1) {
        int v = (t >= off) ? s[t - off] : 0;
        __syncthreads();
        s[t] += v;
        __syncthreads();
    }
    if (t < NBKT) bucket_base[t] = s[t] - own;
}

__global__ __launch_bounds__(256) void k_phase2(const int* __restrict__ rsv,
                                                const int* __restrict__ bucket_base,
                                                const uint2* __restrict__ pairs,
                                                int* __restrict__ csr_e,
                                                int* __restrict__ dv_cnt,
                                                float* __restrict__ dv_isqrt,
                                                int* __restrict__ noff) {
    __shared__ int cnt[128];
    __shared__ int pfx[128];
    __shared__ int curs[128];
    const int t = threadIdx.x;
    const int b = blockIdx.x;
    int sz = rsv[b * RSV_STRIDE];
    if (sz > BCAP) sz = BCAP;
    const int gbase = bucket_base[b];
    const uint2* mp = pairs + (size_t)b * BCAP;
    if (t < 128) cnt[t] = 0;
    __syncthreads();
    for (int i = t; i < sz; i += 256)
        atomicAdd(&cnt[mp[i].x & 127], 1);
    __syncthreads();
    if (t < 128) pfx[t] = cnt[t];
    __syncthreads();
    for (int off = 1; off < 128; off <<= 1) {
        int v = (t < 128 && t >= off) ? pfx[t - off] : 0;
        __syncthreads();
        if (t < 128) pfx[t] += v;
        __syncthreads();
    }
    if (t < 128) {
        int excl = pfx[t] - cnt[t];
        curs[t] = excl;
        int v = (b << 7) + t;
        if (v < N_NODES) {
            int c = cnt[t];
            dv_cnt[v] = c;
            dv_isqrt[v] = (c > 0) ? 1.0f / sqrtf((float)c) : 0.0f;
            noff[v] = gbase + excl;
        }
    }
    __syncthreads();
    for (int i = t; i < sz; i += 256) {
        uint2 p = mp[i];
        int r = atomicAdd(&curs[p.x & 127], 1);
        csr_e[gbase + r] = (int)p.y;
    }
}

// ---------------- X -> bf16 table ----------------

__global__ void k_x2b(const float* __restrict__ X, u16* __restrict__ Xb) {
    int i = blockIdx.x * blockDim.x + threadIdx.x;   // over N_NODES*C1/4 groups
    if (i >= N_NODES * C1 / 4) return;
    float4 x = reinterpret_cast<const float4*>(X)[i];
    reinterpret_cast<ushort4*>(Xb)[i] = make_ushort4(f2b(x.x), f2b(x.y), f2b(x.z), f2b(x.w));
}

// ---------------- feature segment sums (bf16 tables, fp32 accumulate) ----------------
// Wave-per-segment; two 32-lane halves (even/odd incidences), ushort4 (8B) per
// lane -> a 32-lane half reads one full 256B bf16 row per instruction.
// 8-deep unroll per half (16 incidences / wave-iter) keeps bytes-in-flight
// equal to the old fp32 version. Layer-1 variants fuse s = smooth(ones).

template <bool WS>
__global__ void k_gather_edges_b(const int* __restrict__ hoff, const int* __restrict__ de_cnt,
                                 const int* __restrict__ inc_v, const u16* __restrict__ in,
                                 const float* __restrict__ dv_isqrt, const float* __restrict__ de_inv,
                                 u16* __restrict__ out, float* __restrict__ se) {
    int gw = (blockIdx.x * blockDim.x + threadIdx.x) >> 6;
    int lane = threadIdx.x & 63;
    if (gw >= N_HEDGES) return;
    int half = lane >> 5;
    int l = lane & 31;
    int st = hoff[gw], n = de_cnt[gw];
    float4 acc = {0.f, 0.f, 0.f, 0.f};
    float ws = 0.f;
    int j = half;
    for (; j + 14 < n; j += 16) {
        int v[8]; float w[8]; ushort4 r[8];
#pragma unroll
        for (int q = 0; q < 8; ++q) v[q] = inc_v[st + j + 2 * q];
#pragma unroll
        for (int q = 0; q < 8; ++q) w[q] = dv_isqrt[v[q]];
#pragma unroll
        for (int q = 0; q < 8; ++q)
            r[q] = *reinterpret_cast<const ushort4*>(in + (size_t)v[q] * C1 + l * 4);
#pragma unroll
        for (int q = 0; q < 8; ++q) {
            if (WS) ws += w[q];
            float4 x = b4f(r[q]);
            acc.x = fmaf(w[q], x.x, acc.x); acc.y = fmaf(w[q], x.y, acc.y);
            acc.z = fmaf(w[q], x.z, acc.z); acc.w = fmaf(w[q], x.w, acc.w);
        }
    }
    for (; j < n; j += 2) {
        int v = inc_v[st + j];
        float w = dv_isqrt[v];
        float4 x = b4f(*reinterpret_cast<const ushort4*>(in + (size_t)v * C1 + l * 4));
        if (WS) ws += w;
        acc.x = fmaf(w, x.x, acc.x); acc.y = fmaf(w, x.y, acc.y);
        acc.z = fmaf(w, x.z, acc.z); acc.w = fmaf(w, x.w, acc.w);
    }
    acc.x += __shfl_xor(acc.x, 32);
    acc.y += __shfl_xor(acc.y, 32);
    acc.z += __shfl_xor(acc.z, 32);
    acc.w += __shfl_xor(acc.w, 32);
    if (WS) ws += __shfl_xor(ws, 32);
    if (half == 0) {
        float sc = de_inv[gw];
        *reinterpret_cast<ushort4*>(out + (size_t)gw * C1 + l * 4) =
            make_ushort4(f2b(acc.x * sc), f2b(acc.y * sc), f2b(acc.z * sc), f2b(acc.w * sc));
        if (WS && l == 0) se[gw] = ws * sc;
    }
}

// reads bf16 rows, writes fp32 rows (GEMM1 input); SV fuses svec
template <bool SV>
__global__ void k_gather_nodes_b(const int* __restrict__ noff, const int* __restrict__ dv_cnt,
                                 const int* __restrict__ csr_e, const u16* __restrict__ in,
                                 const float* __restrict__ dv_isqrt, float* __restrict__ out,
                                 const float* __restrict__ se, float* __restrict__ svec) {
    int gw = (blockIdx.x * blockDim.x + threadIdx.x) >> 6;
    int lane = threadIdx.x & 63;
    if (gw >= N_NODES) return;
    int half = lane >> 5;
    int l = lane & 31;
    int st = noff[gw], n = dv_cnt[gw];
    float4 acc = {0.f, 0.f, 0.f, 0.f};
    float sv = 0.f;
    int j = half;
    for (; j + 14 < n; j += 16) {
        int e[8]; ushort4 r[8];
#pragma unroll
        for (int q = 0; q < 8; ++q) e[q] = csr_e[st + j + 2 * q];
#pragma unroll
        for (int q = 0; q < 8; ++q)
            r[q] = *reinterpret_cast<const ushort4*>(in + (size_t)e[q] * C1 + l * 4);
#pragma unroll
        for (int q = 0; q < 8; ++q) {
            if (SV) sv += se[e[q]];
            float4 y = b4f(r[q]);
            acc.x += y.x; acc.y += y.y; acc.z += y.z; acc.w += y.w;
        }
    }
    for (; j < n; j += 2) {
        int e = csr_e[st + j];
        float4 y = b4f(*reinterpret_cast<const ushort4*>(in + (size_t)e * C1 + l * 4));
        if (SV) sv += se[e];
        acc.x += y.x; acc.y += y.y; acc.z += y.z; acc.w += y.w;
    }
    acc.x += __shfl_xor(acc.x, 32);
    acc.y += __shfl_xor(acc.y, 32);
    acc.z += __shfl_xor(acc.z, 32);
    acc.w += __shfl_xor(acc.w, 32);
    if (SV) sv += __shfl_xor(sv, 32);
    if (half == 0) {
        float sc = dv_isqrt[gw];
        float4 o = {acc.x * sc, acc.y * sc, acc.z * sc, acc.w * sc};
        *reinterpret_cast<float4*>(out + (size_t)gw * C1 + l * 4) = o;
        if (SV && l == 0) svec[gw] = sv * sc;
    }
}

// final gather + fc head: z never materialized; t[v] = relu(z).fcW
__global__ void k_gather_nodes_fc_b(const int* __restrict__ noff, const int* __restrict__ dv_cnt,
                                    const int* __restrict__ csr_e, const u16* __restrict__ in,
                                    const float* __restrict__ dv_isqrt, const float* __restrict__ fcW,
                                    float* __restrict__ t) {
    int gw = (blockIdx.x * blockDim.x + threadIdx.x) >> 6;
    int lane = threadIdx.x & 63;
    if (gw >= N_NODES) return;
    int half = lane >> 5;
    int l = lane & 31;
    int st = noff[gw], n = dv_cnt[gw];
    float4 acc = {0.f, 0.f, 0.f, 0.f};
    int j = half;
    for (; j + 14 < n; j += 16) {
        int e[8]; ushort4 r[8];
#pragma unroll
        for (int q = 0; q < 8; ++q) e[q] = csr_e[st + j + 2 * q];
#pragma unroll
        for (int q = 0; q < 8; ++q)
            r[q] = *reinterpret_cast<const ushort4*>(in + (size_t)e[q] * C1 + l * 4);
#pragma unroll
        for (int q = 0; q < 8; ++q) {
            float4 y = b4f(r[q]);
            acc.x += y.x; acc.y += y.y; acc.z += y.z; acc.w += y.w;
        }
    }
    for (; j < n; j += 2) {
        int e = csr_e[st + j];
        float4 y = b4f(*reinterpret_cast<const ushort4*>(in + (size_t)e * C1 + l * 4));
        acc.x += y.x; acc.y += y.y; acc.z += y.z; acc.w += y.w;
    }
    acc.x += __shfl_xor(acc.x, 32);
    acc.y += __shfl_xor(acc.y, 32);
    acc.z += __shfl_xor(acc.z, 32);
    acc.w += __shfl_xor(acc.w, 32);
    float sc = dv_isqrt[gw];
    float4 w = *reinterpret_cast<const float4*>(fcW + l * 4);
    float p = fmaxf(acc.x * sc, 0.f) * w.x + fmaxf(acc.y * sc, 0.f) * w.y +
              fmaxf(acc.z * sc, 0.f) * w.z + fmaxf(acc.w * sc, 0.f) * w.w;
#pragma unroll
    for (int off = 16; off > 0; off >>= 1) p += __shfl_xor(p, off);
    if (lane == 0) t[gw] = p;
}

// ---------------- fp32 tiled GEMM, 128x128 tile, 8x8/thread ----------------
// EPI==1: relu(acc + svec[row]*bias[col]) fp32 out
// EPI==3: acc + bias[col], bf16 out (feeds the layer-2 edge gather)
template <int K, int EPI>
__global__ __launch_bounds__(256, 2) void k_gemm(const float* __restrict__ A,
                                                 const float* __restrict__ B,
                                                 const float* __restrict__ bias,
                                                 const float* __restrict__ svec,
                                                 float* __restrict__ C, int M, int N) {
    __shared__ float As[16][132];
    __shared__ float Bs[16][132];
    const int tid = threadIdx.x;
    const int bm = blockIdx.y * 128;
    const int bn = blockIdx.x * 128;
    const int rm = (tid >> 4) * 4;
    const int cn = (tid & 15) * 4;
    float acc[8][8] = {};

    const int arow = tid >> 2;
    const int akc  = (tid & 3) * 4;
    const int brow = tid >> 5;
    const int bcol = (tid & 31) * 4;

    for (int kk = 0; kk < K; kk += 16) {
#pragma unroll
        for (int h = 0; h < 2; ++h) {
            int row = bm + arow + h * 64;
            float4 a = {0.f, 0.f, 0.f, 0.f};
            if (row < M) a = *reinterpret_cast<const float4*>(A + (size_t)row * K + kk + akc);
            As[akc + 0][arow + h * 64] = a.x;
            As[akc + 1][arow + h * 64] = a.y;
            As[akc + 2][arow + h * 64] = a.z;
            As[akc + 3][arow + h * 64] = a.w;
        }
#pragma unroll
        for (int h = 0; h < 2; ++h) {
            int kr = brow + h * 8;
            *reinterpret_cast<float4*>(&Bs[kr][bcol]) =
                *reinterpret_cast<const float4*>(B + (size_t)(kk + kr) * N + bn + bcol);
        }
        __syncthreads();
#pragma unroll
        for (int k = 0; k < 16; ++k) {
            float4 a0 = *reinterpret_cast<const float4*>(&As[k][rm]);
            float4 a1 = *reinterpret_cast<const float4*>(&As[k][64 + rm]);
            float4 b0 = *reinterpret_cast<const float4*>(&Bs[k][cn]);
            float4 b1 = *reinterpret_cast<const float4*>(&Bs[k][64 + cn]);
            float av[8] = {a0.x, a0.y, a0.z, a0.w, a1.x, a1.y, a1.z, a1.w};
            float bv[8] = {b0.x, b0.y, b0.z, b0.w, b1.x, b1.y, b1.z, b1.w};
#pragma unroll
            for (int i = 0; i < 8; ++i)
#pragma unroll
                for (int j = 0; j < 8; ++j)
                    acc[i][j] = fmaf(av[i], bv[j], acc[i][j]);
        }
        __syncthreads();
    }

    const float4 bv0 = *reinterpret_cast<const float4*>(bias + bn + cn);
    const float4 bv1 = *reinterpret_cast<const float4*>(bias + bn + 64 + cn);
    const float bb0[4] = {bv0.x, bv0.y, bv0.z, bv0.w};
    const float bb1[4] = {bv1.x, bv1.y, bv1.z, bv1.w};
#pragma unroll
    for (int i = 0; i < 8; ++i) {
        int row = bm + ((i < 4) ? (rm + i) : (64 + rm + i - 4));
        if (row >= M) continue;
        float s = (EPI == 1) ? svec[row] : 0.f;
        float v0[4], v1[4];
#pragma unroll
        for (int j = 0; j < 4; ++j) {
            if (EPI == 1) {
                v0[j] = fmaxf(fmaf(s, bb0[j], acc[i][j]), 0.f);
                v1[j] = fmaxf(fmaf(s, bb1[j], acc[i][j + 4]), 0.f);
            } else {
                v0[j] = acc[i][j] + bb0[j];
                v1[j] = acc[i][j + 4] + bb1[j];
            }
        }
        if (EPI == 3) {
            u16* Cb = (u16*)C;
            *reinterpret_cast<ushort4*>(Cb + (size_t)row * N + bn + cn) =
                make_ushort4(f2b(v0[0]), f2b(v0[1]), f2b(v0[2]), f2b(v0[3]));
            *reinterpret_cast<ushort4*>(Cb + (size_t)row * N + bn + 64 + cn) =
                make_ushort4(f2b(v1[0]), f2b(v1[1]), f2b(v1[2]), f2b(v1[3]));
        } else {
            float4 o0 = {v0[0], v0[1], v0[2], v0[3]};
            float4 o1 = {v1[0], v1[1], v1[2], v1[3]};
            *reinterpret_cast<float4*>(C + (size_t)row * N + bn + cn) = o0;
            *reinterpret_cast<float4*>(C + (size_t)row * N + bn + 64 + cn) = o1;
        }
    }
}

// ---------------- link head ----------------

__global__ void k_link(const int* __restrict__ link, const float* __restrict__ t,
                       const float* __restrict__ fcb, float* __restrict__ out) {
    int l = blockIdx.x * blockDim.x + threadIdx.x;
    if (l >= N_LINKS) return;
    int a = link[2 * l], b = link[2 * l + 1];
    float x = 0.5f * (t[a] + t[b]) + fcb[0];
    out[l] = 1.f / (1.f + expf(-x));
}

// ---------------- host ----------------

extern "C" void kernel_launch(void* const* d_in, const int* in_sizes, int n_in,
                              void* d_out, int out_size, void* d_ws, size_t ws_size,
                              hipStream_t stream) {
    const float* X    = (const float*)d_in[0];
    const float* W1   = (const float*)d_in[1];
    const float* b1   = (const float*)d_in[2];
    const float* W2   = (const float*)d_in[3];
    const float* b2   = (const float*)d_in[4];
    const float* fcW  = (const float*)d_in[5];
    const float* fcb  = (const float*)d_in[6];
    const int* inc_v  = (const int*)d_in[7];
    const int* inc_e  = (const int*)d_in[8];
    const int* link   = (const int*)d_in[9];
    float* out = (float*)d_out;

    size_t off = 0;
    auto carve = [&](size_t nbytes) -> void* {
        void* p = (char*)d_ws + off;
        off += (nbytes + 255) & ~(size_t)255;
        return p;
    };
    int* hoff    = (int*)carve((size_t)N_HEDGES * 4);
    int* hend    = (int*)carve((size_t)N_HEDGES * 4);
    int* de_cnt  = (int*)carve((size_t)N_HEDGES * 4);
    int* dv_cnt  = (int*)carve((size_t)N_NODES * 4);
    int* noff    = (int*)carve((size_t)N_NODES * 4);
    int* rsv     = (int*)carve((size_t)NBKT * RSV_STRIDE * 4);
    int* bucket_base = (int*)carve((size_t)NBKT * 4);
    float* dv_isqrt = (float*)carve((size_t)N_NODES * 4);
    float* de_inv   = (float*)carve((size_t)N_HEDGES * 4);
    float* se    = (float*)carve((size_t)N_HEDGES * 4);
    float* svec  = (float*)carve((size_t)N_NODES * 4);
    float* tvec  = (float*)carve((size_t)N_NODES * 4);
    int* csr_e   = (int*)carve((size_t)N_INC * 4);
    // R0 (102.4 MB) time-shares: pairs (51.2MB) -> Yeb1 (25.6MB) -> H (full)
    //   -> Yeb2 (25.6MB).  Xs (51.2MB fp32) time-shares: Xb (25.6MB bf16, dead
    //   before node-gather-1 writes Xs) -> Xs fp32 (GEMM1 input) -> T2b
    //   (25.6MB bf16, GEMM2 output; Xs fp32 dead after GEMM1).
    float* R0    = (float*)carve((size_t)N_NODES * 256 * 4);   // 102.4 MB
    float* Xs    = (float*)carve((size_t)N_NODES * C1 * 4);    // 51.2 MB
    uint2* pairs = (uint2*)R0;
    u16*   Yeb   = (u16*)R0;
    float* H     = R0;
    u16*   Xb    = (u16*)Xs;
    u16*   T2b   = (u16*)Xs;

    if (off > ws_size) return;   // clean, attributable failure instead of OOB

    // structure
    k_init2<<<(N_HEDGES + 255) / 256, 256, 0, stream>>>(hoff, hend, rsv);
    k_boundary<<<N_INC / 256, 256, 0, stream>>>(inc_e, hoff, hend);
    k_transform_e<<<(N_HEDGES + 255) / 256, 256, 0, stream>>>(hoff, hend, de_cnt, de_inv);
    k_phase1<<<P1_NB, 256, 0, stream>>>(inc_v, inc_e, rsv, pairs);
    k_scan_buckets<<<1, 1024, 0, stream>>>(rsv, bucket_base);
    k_phase2<<<NBKT, 256, 0, stream>>>(rsv, bucket_base, pairs, csr_e, dv_cnt, dv_isqrt, noff);

    // bf16 feature table for layer-1 gather
    k_x2b<<<(N_NODES * C1 / 4 + 255) / 256, 256, 0, stream>>>(X, Xb);

    // layer 1: h = relu(smooth(X) @ W1 + s*b1); s = smooth(ones) fused (WS/SV)
    k_gather_edges_b<true><<<25000, 256, 0, stream>>>(hoff, de_cnt, inc_v, Xb, dv_isqrt, de_inv, Yeb, se);
    k_gather_nodes_b<true><<<25000, 256, 0, stream>>>(noff, dv_cnt, csr_e, Yeb, dv_isqrt, Xs, se, svec);
    k_gemm<128, 1><<<dim3(2, (N_NODES + 127) / 128), 256, 0, stream>>>(Xs, W1, b1, svec, H, N_NODES, 256);

    // layer 2: z = relu(smooth(H @ W2 + b2)); GEMM2 emits bf16; fc fused
    k_gemm<256, 3><<<dim3(1, (N_NODES + 127) / 128), 256, 0, stream>>>(H, W2, b2, nullptr, (float*)T2b, N_NODES, 128);
    k_gather_edges_b<false><<<25000, 256, 0, stream>>>(hoff, de_cnt, inc_v, T2b, dv_isqrt, de_inv, Yeb, nullptr);
    k_gather_nodes_fc_b<<<25000, 256, 0, stream>>>(noff, dv_cnt, csr_e, Yeb, dv_isqrt, fcW, tvec);

    // out = sigmoid(0.5*(t[a]+t[b]) + fcb)
    k_link<<<N_LINKS / 256, 256, 0, stream>>>(link, tvec, fcb, out);
}